// Round 14
// baseline (254.067 us; speedup 1.0000x reference)
//
#include <hip/hip_runtime.h>
#include <math.h>

#define D_   512
#define H_   8
#define DK_  64
#define FF_  2048
#define S_   2048
#define B_   4
#define M_   (B_*S_)     // 8192
#define EPS_ 1e-5f
#define SCLQ 0.1803368801111f   // 0.125 * log2(e): folded into wq/bq at prep

typedef __attribute__((ext_vector_type(8))) short bf16x8;
typedef __attribute__((ext_vector_type(4))) short bf16x4;
typedef __attribute__((ext_vector_type(4))) float f32x4;
typedef __attribute__((ext_vector_type(4))) unsigned int u32x4;

__device__ inline unsigned short f2b(float f) {
    unsigned u = __builtin_bit_cast(unsigned, f);
    unsigned r = (u + 0x7FFFu + ((u >> 16) & 1u)) >> 16;
    return (unsigned short)r;
}
__device__ inline float b2f(unsigned short u) {
    return __builtin_bit_cast(float, (unsigned)u << 16);
}
// pack bf16(p0) low half, bf16(p1) high half — round-to-nearest-even via HW
__device__ inline unsigned packbf(float p0, float p1) {
    unsigned r;
    asm("v_cvt_pk_bf16_f32 %0, %1, %2" : "=v"(r) : "v"(p0), "v"(p1));
    return r;
}

// async 16B global->LDS. LDS dest must be wave-uniform base + lane*16.
__device__ __forceinline__ void async_cp16(const void* g, void* l) {
    __builtin_amdgcn_global_load_lds(
        (const __attribute__((address_space(1))) unsigned int*)g,
        (__attribute__((address_space(3))) unsigned int*)l, 16, 0, 0);
}

// ---------------------------------------------------------------------------
// Unified preprocessing (1 dispatch, 5120 blocks).
// ---------------------------------------------------------------------------
__global__ __launch_bounds__(256)
void prep_kernel(const float* __restrict__ x,
                 const float* __restrict__ wq, const float* __restrict__ wk,
                 const float* __restrict__ wv, const float* __restrict__ wo,
                 const float* __restrict__ bq, const float* __restrict__ bk,
                 const float* __restrict__ bv,
                 const float* __restrict__ w1, const float* __restrict__ w2,
                 unsigned short* __restrict__ xb, unsigned short* __restrict__ wqkvt,
                 unsigned short* __restrict__ wot, unsigned short* __restrict__ w1t,
                 unsigned short* __restrict__ w2t, float* __restrict__ bqkv)
{
    __shared__ float L[32][33];
    const int bid = blockIdx.x;
    const int tid = threadIdx.x;

    if (bid < 2048) {                       // x -> xb
        const int i = (bid * 256 + tid) * 8;
        const float4 a = *(const float4*)(x + i);
        const float4 b = *(const float4*)(x + i + 4);
        bf16x8 v;
        v[0] = (short)f2b(a.x); v[1] = (short)f2b(a.y);
        v[2] = (short)f2b(a.z); v[3] = (short)f2b(a.w);
        v[4] = (short)f2b(b.x); v[5] = (short)f2b(b.y);
        v[6] = (short)f2b(b.z); v[7] = (short)f2b(b.w);
        *(bf16x8*)(xb + i) = v;
        return;
    }

    const float* w; unsigned short* wt; int K, N, k0, n0; float scl = 1.f;
    if (bid < 3072) {
        const int z = (bid - 2048) >> 8;
        const int r = (bid - 2048) & 255;
        n0 = (r & 15) * 32; k0 = (r >> 4) * 32; K = 512; N = 512;
        w  = (z == 0) ? wq : (z == 1) ? wk : (z == 2) ? wv : wo;
        wt = (z < 3) ? (wqkvt + (size_t)z * 512 * 512) : wot;
        if (z == 0) scl = SCLQ;
        if (z < 3 && r == 0) {
            const float* bsrc = (z == 0) ? bq : (z == 1) ? bk : bv;
            const float bscl  = (z == 0) ? SCLQ : 1.f;
            bqkv[z * 512 + tid]       = bsrc[tid] * bscl;
            bqkv[z * 512 + 256 + tid] = bsrc[256 + tid] * bscl;
        }
    } else if (bid < 4096) {
        const int r = bid - 3072;
        n0 = (r & 63) * 32; k0 = (r >> 6) * 32; K = 512; N = 2048;
        w = w1; wt = w1t;
    } else {
        const int r = bid - 4096;
        n0 = (r & 15) * 32; k0 = (r >> 4) * 32; K = 2048; N = 512;
        w = w2; wt = w2t;
    }

    const int xx = tid & 31, y = tid >> 5;
#pragma unroll
    for (int i = 0; i < 4; i++)
        L[y + i * 8][xx] = w[(size_t)(k0 + y + i * 8) * N + n0 + xx] * scl;
    __syncthreads();
#pragma unroll
    for (int i = 0; i < 4; i++)
        wt[(size_t)(n0 + y + i * 8) * K + k0 + xx] = f2b(L[xx][y + i * 8]);
}

// ---------------------------------------------------------------------------
// bf16 MFMA GEMM, double-buffered (prefetch + partial vmcnt + raw s_barrier).
// BK: K-depth staged per barrier-pair. BK=64's 128B LDS rows are XOR-swizzled
// (source-side) against bank conflicts. Tile 64x128 everywhere (r11: 128x128
// at BK=64 = 64KB LDS = 2 blocks/CU occupancy cliff, 255->263; don't re-raise).
// XCD-aware block swizzle (T1): remap lin -> (lin%8)*(nwg/8) + lin/8 so each
// XCD L2 gets a contiguous chunk of complete A-panel groups (r2: ffn2 FETCH
// 78MB vs 34MB ideal from round-robin panel re-fetch). nwg%8==0 all grids.
// SPLITK: blockIdx.z selects a K-half (K arg = half length); z=0 -> Cv,
// z=1 -> Cv2, both raw fp32 partials (no bias/res/relu) — combined in the
// fused LN. Doubles resident blocks on the serial ffn2 shape (2->3/CU+queue).
// RESADD: 0 none, 1 fp32 residual, 2 bf16 residual (C-layout indexed).
// In-place RES==Cv is safe: each idx is read-then-written by one thread.
// VT: cols >= 1024 are the V-projection — written TRANSPOSED into
// vtout[(b*512 + (col-1024))][s] as one short4 (4 consecutive s).
// ---------------------------------------------------------------------------
template<int WR, int WC, int MT, int NT, int BK, int OUTB, int RELU, int RESADD, int HASBIAS, int VT, int SPLITK>
__global__ __launch_bounds__(256)
void gemm_bf16(const unsigned short* __restrict__ A, const unsigned short* __restrict__ Bt,
               const float* __restrict__ bias, const void* __restrict__ RES,
               void* __restrict__ Cv, unsigned short* __restrict__ vtout,
               float* __restrict__ Cv2,
               int K, int lda, int ldb, int ldc)
{
    constexpr int BM  = WR * MT * 16;
    constexpr int BN  = WC * NT * 16;
    constexpr int CPR = BK / 8;              // 16B chunks per LDS row
    constexpr int CA  = BM * BK / (256 * 8);
    constexpr int CB  = BN * BK / (256 * 8);
    __shared__ unsigned short As[2][BM * BK];
    __shared__ unsigned short Bs[2][BN * BK];

    const int tid  = threadIdx.x;
    const int lane = tid & 63;
    const int w    = tid >> 6;
    const int wr   = w / WC, wc = w % WC;
    const int quad = lane >> 4;
    const int l15  = lane & 15;

    // XCD-aware swizzle over (x,y); z (split-K) planes swizzle identically.
    const int nwg = gridDim.x * gridDim.y;
    const int lin = blockIdx.y * gridDim.x + blockIdx.x;
    const int swz = (lin & 7) * (nwg >> 3) + (lin >> 3);
    const int n0  = (swz % gridDim.x) * BN;
    const int m0  = (swz / gridDim.x) * BM;
    const int koff = SPLITK ? blockIdx.z * K : 0;

    f32x4 acc[MT][NT];
#pragma unroll
    for (int i = 0; i < MT; i++)
#pragma unroll
        for (int j = 0; j < NT; j++) acc[i][j] = (f32x4){0.f, 0.f, 0.f, 0.f};

    auto stage = [&](int k0, int bufi) {
#pragma unroll
        for (int i = 0; i < CA; i++) {
            const int c   = tid + i * 256;
            const int row = c / CPR;
            int l = c % CPR;
            if (BK == 64) l ^= (row & 7);    // source-side swizzle, LDS linear
            async_cp16(&A[(size_t)(m0 + row) * lda + koff + k0 + l * 8], &As[bufi][c * 8]);
        }
#pragma unroll
        for (int i = 0; i < CB; i++) {
            const int c   = tid + i * 256;
            const int row = c / CPR;
            int l = c % CPR;
            if (BK == 64) l ^= (row & 7);
            async_cp16(&Bt[(size_t)(n0 + row) * ldb + koff + k0 + l * 8], &Bs[bufi][c * 8]);
        }
    };

    stage(0, 0);
    const int niter = K / BK;
    for (int ii = 0; ii < niter; ii++) {
        const int knext = (ii + 1 < niter) ? (ii + 1) * BK : 0;
        stage(knext, (ii + 1) & 1);
        __builtin_amdgcn_s_waitcnt(0x0f70 | (CA + CB));
        __builtin_amdgcn_s_barrier();

        const unsigned short* Ac = &As[ii & 1][0];
        const unsigned short* Bc = &Bs[ii & 1][0];
#pragma unroll
        for (int ks = 0; ks < BK / 32; ks++) {
            bf16x8 af[MT], bfr[NT];
#pragma unroll
            for (int t = 0; t < MT; t++) {
                const int r = wr * MT * 16 + t * 16 + l15;
                int ch = (ks << 2) | quad;
                if (BK == 64) ch ^= (r & 7);
                af[t] = *(const bf16x8*)&Ac[r * BK + ch * 8];
            }
#pragma unroll
            for (int t = 0; t < NT; t++) {
                const int r = wc * NT * 16 + t * 16 + l15;
                int ch = (ks << 2) | quad;
                if (BK == 64) ch ^= (r & 7);
                bfr[t] = *(const bf16x8*)&Bc[r * BK + ch * 8];
            }
#pragma unroll
            for (int mt = 0; mt < MT; mt++)
#pragma unroll
                for (int nt = 0; nt < NT; nt++)
                    acc[mt][nt] = __builtin_amdgcn_mfma_f32_16x16x32_bf16(
                        af[mt], bfr[nt], acc[mt][nt], 0, 0, 0);
        }
        __builtin_amdgcn_s_barrier();
    }

    // epilogue: C/D layout col=lane&15, row=quad*4+reg
#pragma unroll
    for (int mt = 0; mt < MT; mt++) {
        const int rowb = m0 + wr * MT * 16 + mt * 16 + quad * 4;
#pragma unroll
        for (int nt = 0; nt < NT; nt++) {
            const int col = n0 + wc * NT * 16 + nt * 16 + l15;
            if (SPLITK) {
                float* dst = blockIdx.z ? Cv2 : (float*)Cv;
#pragma unroll
                for (int r = 0; r < 4; r++)
                    dst[(size_t)(rowb + r) * ldc + col] = acc[mt][nt][r];
                continue;
            }
            const float bv = HASBIAS ? bias[col] : 0.f;
            if (VT && col >= 1024) {
                // V-projection: transposed bf16 write, one short4 (4 s-values)
                short4 sv;
                sv.x = (short)f2b(acc[mt][nt][0] + bv);
                sv.y = (short)f2b(acc[mt][nt][1] + bv);
                sv.z = (short)f2b(acc[mt][nt][2] + bv);
                sv.w = (short)f2b(acc[mt][nt][3] + bv);
                const int bb = rowb >> 11;           // batch (row/2048); uniform per block
                *(short4*)&vtout[(size_t)(bb * 512 + (col - 1024)) * S_ + (rowb & 2047)] = sv;
            } else {
#pragma unroll
                for (int r = 0; r < 4; r++) {
                    const size_t idx = (size_t)(rowb + r) * ldc + col;
                    float v = acc[mt][nt][r] + bv;
                    if (RESADD == 1) v += ((const float*)RES)[idx];
                    if (RESADD == 2) v += b2f(((const unsigned short*)RES)[idx]);
                    if (RELU)   v = fmaxf(v, 0.f);
                    if (OUTB) ((unsigned short*)Cv)[idx] = f2b(v);
                    else      ((float*)Cv)[idx] = v;
                }
            }
        }
    }
}

// ---------------------------------------------------------------------------
// Causal flash attention, K-SPLIT register-P, ZERO-SHUFFLE PV.
// BQ=64, KB=64, grid 1024, 4 waves/block. Wave w = (qh=w>>1, kh=w&1):
// 32 queries x 32 keys, 2 q-tiles sharing every K/V ds_read.
// Softmax->PV handoff with NO transpose: QK^T (S^T trick) leaves lane l with
// P[k=quad*4+r][q=l15]; the A-fragment of v_mfma_f32_16x16x16_bf16 is
// A[m=l15][k=quad*4+j] — the SAME lane mapping (m=q, j=r). PV runs as
// 2x K=16 MFMAs per 32-k chunk with the packed exp2 output used directly.
// Work balance: CU hosts bids {c,c+256,c+512,c+768}; qb(g) makes every
// quadruple sum to 62 tile-iters. Same-bh blocks are stride-32 apart
// (32%8==0) -> already co-located per XCD; no swizzle needed here.
// ---------------------------------------------------------------------------
__global__ __launch_bounds__(256, 4)
void attn_mfma(const unsigned short* __restrict__ qkv,
               const unsigned short* __restrict__ vt,
               unsigned short* __restrict__ ctx)
{
    // Arena (32 KB): [0..8191] Ks dbuf [kr][d] chunk^=(kr&7);
    // [8192..16383] Vs dbuf [dk][kr] chunk^=(dk&7).
    // First 22.5 KB reused as f32 reduction scratch at the end.
    __shared__ unsigned short Arena[16384];

    const int tid  = threadIdx.x;
    const int lane = tid & 63;
    const int w    = tid >> 6;                  // 0..3
    const int quad = lane >> 4;
    const int l15  = lane & 15;
    const int bid  = blockIdx.x;
    const int g    = bid >> 5;
    // CU-balanced qb permutation (bijective over g=0..31)
    const int qb   = (g < 8) ? 31 - g : (g < 16) ? g + 8 : (g < 24) ? 31 - g : g - 24;
    const int bh   = bid & 31;
    const int b    = bh >> 3, hh = bh & 7;
    const int kh   = w & 1;                     // k-chunk (32 keys)
    const int qh   = w >> 1;                    // q-half (32 queries)

    const unsigned short* qbase = qkv + (size_t)(b * S_) * 1536 + hh * 64;
    const unsigned short* kbase = qbase + 512;
    const unsigned short* vtb   = vt + (size_t)bh * 64 * S_;

    bf16x4 ones4;
#pragma unroll
    for (int j = 0; j < 4; j++) ones4[j] = (short)0x3F80;

    auto stage = [&](int kb, int bufi) {
        unsigned short* kd = &Arena[bufi * 4096];
        unsigned short* vd = &Arena[8192 + bufi * 4096];
#pragma unroll
        for (int i = 0; i < 2; i++) {
            const int c = tid + i * 256;
            const int row = c >> 3;
            const int l = (c & 7) ^ (row & 7);
            async_cp16(kbase + (size_t)(kb * 64 + row) * 1536 + l * 8, kd + c * 8);
            async_cp16(vtb + (size_t)row * S_ + kb * 64 + l * 8, vd + c * 8);
        }
    };

    // Q fragments: 2 q-tiles x 2 kc (d chunks)
    bf16x8 qf[2][2];
#pragma unroll
    for (int qt = 0; qt < 2; qt++) {
        const unsigned short* qr = qbase + (size_t)(qb * 64 + qh * 32 + qt * 16 + l15) * 1536;
        qf[qt][0] = *(const bf16x8*)(qr + quad * 8);
        qf[qt][1] = *(const bf16x8*)(qr + 32 + quad * 8);
    }

    f32x4 Oacc[2][5];                           // [qt][0..3]=O dk-tiles, [4]=row-sum
#pragma unroll
    for (int qt = 0; qt < 2; qt++)
#pragma unroll
        for (int i = 0; i < 5; i++) Oacc[qt][i] = (f32x4){0.f, 0.f, 0.f, 0.f};

    stage(0, 0);

    // V b64 fragment address (shorts): per (kt,nt), kr = kh*32+kt*16+quad*4
    const int vch0 = (kh * 4 + (quad >> 1));    // ^(l15&7) applied per read
    const int vsub = (quad & 1) * 4;

    // ---- main loop (kb < qb): no masking
    for (int kb = 0; kb < qb; kb++) {
        stage(kb + 1, (kb + 1) & 1);
        __builtin_amdgcn_s_waitcnt(0x0F74);     // vmcnt(4): current tile done
        __builtin_amdgcn_s_barrier();
        const unsigned short* Kc = &Arena[(kb & 1) * 4096];
        const unsigned short* Vc = &Arena[8192 + (kb & 1) * 4096];

        f32x4 st[2][2];                         // [qt][kt]
#pragma unroll
        for (int qt = 0; qt < 2; qt++)
#pragma unroll
            for (int kt = 0; kt < 2; kt++) st[qt][kt] = (f32x4){0.f, 0.f, 0.f, 0.f};
#pragma unroll
        for (int kc = 0; kc < 2; kc++) {
            const int phys = (kc * 4 + quad) ^ (l15 & 7);
            const bf16x8 kf0 = *(const bf16x8*)&Kc[(kh * 32 + l15) * 64 + phys * 8];
            const bf16x8 kf1 = *(const bf16x8*)&Kc[(kh * 32 + 16 + l15) * 64 + phys * 8];
#pragma unroll
            for (int qt = 0; qt < 2; qt++) {
                st[qt][0] = __builtin_amdgcn_mfma_f32_16x16x32_bf16(kf0, qf[qt][kc], st[qt][0], 0, 0, 0);
                st[qt][1] = __builtin_amdgcn_mfma_f32_16x16x32_bf16(kf1, qf[qt][kc], st[qt][1], 0, 0, 0);
            }
        }

        // V fragments: b64 per (kt,nt)
        bf16x4 vf[2][4];
#pragma unroll
        for (int kt = 0; kt < 2; kt++)
#pragma unroll
            for (int nt = 0; nt < 4; nt++)
                vf[kt][nt] = *(const bf16x4*)&Vc[(nt * 16 + l15) * 64 +
                    (((vch0 + kt * 2) ^ (l15 & 7)) << 3) + vsub];

        // P directly in registers as K=16 A-fragments
#pragma unroll
        for (int qt = 0; qt < 2; qt++) {
#pragma unroll
            for (int kt = 0; kt < 2; kt++) {
                uint2 aw;
                aw.x = packbf(exp2f(st[qt][kt][0]), exp2f(st[qt][kt][1]));
                aw.y = packbf(exp2f(st[qt][kt][2]), exp2f(st[qt][kt][3]));
                const bf16x4 af = __builtin_bit_cast(bf16x4, aw);
#pragma unroll
                for (int nt = 0; nt < 4; nt++)
                    Oacc[qt][nt] = __builtin_amdgcn_mfma_f32_16x16x16bf16_1k(
                        af, vf[kt][nt], Oacc[qt][nt], 0, 0, 0);
                Oacc[qt][4] = __builtin_amdgcn_mfma_f32_16x16x16bf16_1k(
                    af, ones4, Oacc[qt][4], 0, 0, 0);
            }
        }
        __builtin_amdgcn_s_barrier();           // reads done before re-stage
    }

    // ---- peeled diagonal iteration (kb == qb)
    {
        stage(0, (qb + 1) & 1);                 // dummy prefetch (vmcnt uniform)
        __builtin_amdgcn_s_waitcnt(0x0F74);
        __builtin_amdgcn_s_barrier();
        const unsigned short* Kc = &Arena[(qb & 1) * 4096];
        const unsigned short* Vc = &Arena[8192 + (qb & 1) * 4096];

        const bool skipDiag = (kh == 1 && qh == 0);   // k 32..63 > q 0..31: all masked
        const bool fullDiag = (kh == 0 && qh == 1);   // k 0..31 < q 32..63: no mask

        if (!skipDiag) {
            f32x4 st[2][2];
#pragma unroll
            for (int qt = 0; qt < 2; qt++)
#pragma unroll
                for (int kt = 0; kt < 2; kt++) st[qt][kt] = (f32x4){0.f, 0.f, 0.f, 0.f};
#pragma unroll
            for (int kc = 0; kc < 2; kc++) {
                const int phys = (kc * 4 + quad) ^ (l15 & 7);
                const bf16x8 kf0 = *(const bf16x8*)&Kc[(kh * 32 + l15) * 64 + phys * 8];
                const bf16x8 kf1 = *(const bf16x8*)&Kc[(kh * 32 + 16 + l15) * 64 + phys * 8];
#pragma unroll
                for (int qt = 0; qt < 2; qt++) {
                    st[qt][0] = __builtin_amdgcn_mfma_f32_16x16x32_bf16(kf0, qf[qt][kc], st[qt][0], 0, 0, 0);
                    st[qt][1] = __builtin_amdgcn_mfma_f32_16x16x32_bf16(kf1, qf[qt][kc], st[qt][1], 0, 0, 0);
                }
            }

            // per-(qt,kt) tile class: fullDiag -> all full;
            // else (kh==qh): (0,0) tri, (0,1) zero, (1,0) full, (1,1) tri.
            bf16x4 af[2][2];
            if (fullDiag) {
#pragma unroll
                for (int qt = 0; qt < 2; qt++)
#pragma unroll
                    for (int kt = 0; kt < 2; kt++) {
                        uint2 aw;
                        aw.x = packbf(exp2f(st[qt][kt][0]), exp2f(st[qt][kt][1]));
                        aw.y = packbf(exp2f(st[qt][kt][2]), exp2f(st[qt][kt][3]));
                        af[qt][kt] = __builtin_bit_cast(bf16x4, aw);
                    }
            } else {
                float p[4];
                uint2 aw;
#pragma unroll
                for (int r = 0; r < 4; r++)
                    p[r] = (quad * 4 + r > l15) ? 0.f : exp2f(st[0][0][r]);
                aw.x = packbf(p[0], p[1]); aw.y = packbf(p[2], p[3]);
                af[0][0] = __builtin_bit_cast(bf16x4, aw);
                af[0][1] = (bf16x4){0, 0, 0, 0};
                aw.x = packbf(exp2f(st[1][0][0]), exp2f(st[1][0][1]));
                aw.y = packbf(exp2f(st[1][0][2]), exp2f(st[1][0][3]));
                af[1][0] = __builtin_bit_cast(bf16x4, aw);
#pragma unroll
                for (int r = 0; r < 4; r++)
                    p[r] = (quad * 4 + r > l15) ? 0.f : exp2f(st[1][1][r]);
                aw.x = packbf(p[0], p[1]); aw.y = packbf(p[2], p[3]);
                af[1][1] = __builtin_bit_cast(bf16x4, aw);
            }

            bf16x4 vf[2][4];
#pragma unroll
            for (int kt = 0; kt < 2; kt++)
#pragma unroll
                for (int nt = 0; nt < 4; nt++)
                    vf[kt][nt] = *(const bf16x4*)&Vc[(nt * 16 + l15) * 64 +
                        (((vch0 + kt * 2) ^ (l15 & 7)) << 3) + vsub];

#pragma unroll
            for (int qt = 0; qt < 2; qt++)
#pragma unroll
                for (int kt = 0; kt < 2; kt++) {
#pragma unroll
                    for (int nt = 0; nt < 4; nt++)
                        Oacc[qt][nt] = __builtin_amdgcn_mfma_f32_16x16x16bf16_1k(
                            af[qt][kt], vf[kt][nt], Oacc[qt][nt], 0, 0, 0);
                    Oacc[qt][4] = __builtin_amdgcn_mfma_f32_16x16x16bf16_1k(
                        af[qt][kt], ones4, Oacc[qt][4], 0, 0, 0);
                }
        }
    }

    // ---- cross-wave reduction (kh=1 partials -> kh=0), then write ctx
    __syncthreads();
    float* red = (float*)&Arena[0];             // 2 regions x 64 lanes x 44 floats = 22.5 KB
    const int rbase = (qh * 64 + lane) * 44;
    if (kh) {
#pragma unroll
        for (int qt = 0; qt < 2; qt++)
#pragma unroll
            for (int i = 0; i < 5; i++)
                *(f32x4*)&red[rbase + (qt * 5 + i) * 4] = Oacc[qt][i];
    }
    __syncthreads();
    if (!kh) {
#pragma unroll
        for (int qt = 0; qt < 2; qt++)
#pragma unroll
            for (int i = 0; i < 5; i++)
                Oacc[qt][i] += *(const f32x4*)&red[rbase + (qt * 5 + i) * 4];

        unsigned short* cb = ctx + (size_t)(b * S_) * 512 + hh * 64;
#pragma unroll
        for (int qt = 0; qt < 2; qt++) {
            const int orow = qb * 64 + qh * 32 + qt * 16 + quad * 4;
#pragma unroll
            for (int r = 0; r < 4; r++) {
                const float inv = 1.f / Oacc[qt][4][r];
#pragma unroll
                for (int nt = 0; nt < 4; nt++)
                    cb[(size_t)(orow + r) * 512 + nt * 16 + l15] = f2b(Oacc[qt][nt][r] * inv);
            }
        }
    }
}

// ---------------------------------------------------------------------------
// LayerNorm: WF -> fp32 out, WB -> bf16 out. 1 wave/row.
// COMB: input row = s + s2 + bias2 + bf16(resb) (split-K combine for ffn2).
// In-place (s == out) is safe: reads complete before writes per thread.
// ---------------------------------------------------------------------------
template<int WF, int WB, int COMB>
__global__ __launch_bounds__(256)
void ln_kernel(const float* __restrict__ s, const float* __restrict__ g,
               const float* __restrict__ be, float* __restrict__ out,
               unsigned short* __restrict__ outb,
               const float* __restrict__ s2, const unsigned short* __restrict__ resb,
               const float* __restrict__ bias2)
{
    const int wave = threadIdx.x >> 6;
    const int lane = threadIdx.x & 63;
    const int row  = blockIdx.x * 4 + wave;
    const float* ps = s + (size_t)row * D_;
    const int c0 = lane * 4;

    float v[8];
    {
        const float4 a0 = *(const float4*)(ps + c0);
        const float4 a1 = *(const float4*)(ps + c0 + 256);
        v[0] = a0.x; v[1] = a0.y; v[2] = a0.z; v[3] = a0.w;
        v[4] = a1.x; v[5] = a1.y; v[6] = a1.z; v[7] = a1.w;
    }
    if (COMB) {
        const float* ps2 = s2 + (size_t)row * D_;
        const float4 c00 = *(const float4*)(ps2 + c0);
        const float4 c1 = *(const float4*)(ps2 + c0 + 256);
        const float4 bb0 = *(const float4*)(bias2 + c0);
        const float4 bb1 = *(const float4*)(bias2 + c0 + 256);
        const short4 r0 = *(const short4*)(resb + (size_t)row * D_ + c0);
        const short4 r1 = *(const short4*)(resb + (size_t)row * D_ + c0 + 256);
        v[0] += c00.x + bb0.x + b2f((unsigned short)r0.x);
        v[1] += c00.y + bb0.y + b2f((unsigned short)r0.y);
        v[2] += c00.z + bb0.z + b2f((unsigned short)r0.z);
        v[3] += c00.w + bb0.w + b2f((unsigned short)r0.w);
        v[4] += c1.x + bb1.x + b2f((unsigned short)r1.x);
        v[5] += c1.y + bb1.y + b2f((unsigned short)r1.y);
        v[6] += c1.z + bb1.z + b2f((unsigned short)r1.z);
        v[7] += c1.w + bb1.w + b2f((unsigned short)r1.w);
    }

    float sum = 0.f;
#pragma unroll
    for (int i = 0; i < 8; i++) sum += v[i];
#pragma unroll
    for (int m = 1; m < 64; m <<= 1) sum += __shfl_xor(sum, m);
    const float mu = sum * (1.f / D_);

    float sq = 0.f;
#pragma unroll
    for (int i = 0; i < 8; i++) { const float d = v[i] - mu; sq += d * d; }
#pragma unroll
    for (int m = 1; m < 64; m <<= 1) sq += __shfl_xor(sq, m);
    const float rstd = rsqrtf(sq * (1.f / D_) + EPS_);

    const float4 g0 = *(const float4*)(g + c0);
    const float4 b0 = *(const float4*)(be + c0);
    const float4 g1 = *(const float4*)(g + c0 + 256);
    const float4 b1 = *(const float4*)(be + c0 + 256);

    float o[8];
    o[0] = (v[0] - mu) * rstd * g0.x + b0.x;
    o[1] = (v[1] - mu) * rstd * g0.y + b0.y;
    o[2] = (v[2] - mu) * rstd * g0.z + b0.z;
    o[3] = (v[3] - mu) * rstd * g0.w + b0.w;
    o[4] = (v[4] - mu) * rstd * g1.x + b1.x;
    o[5] = (v[5] - mu) * rstd * g1.y + b1.y;
    o[6] = (v[6] - mu) * rstd * g1.z + b1.z;
    o[7] = (v[7] - mu) * rstd * g1.w + b1.w;

    if (WF) {
        *(float4*)(out + (size_t)row * D_ + c0)       = *(float4*)&o[0];
        *(float4*)(out + (size_t)row * D_ + c0 + 256) = *(float4*)&o[4];
    }
    if (WB) {
        short4 vb0 = (short4){(short)f2b(o[0]), (short)f2b(o[1]), (short)f2b(o[2]), (short)f2b(o[3])};
        short4 vb1 = (short4){(short)f2b(o[4]), (short)f2b(o[5]), (short)f2b(o[6]), (short)f2b(o[7])};
        *(short4*)(outb + (size_t)row * D_ + c0)       = vb0;
        *(short4*)(outb + (size_t)row * D_ + c0 + 256) = vb1;
    }
}

// ---------------------------------------------------------------------------
extern "C" void kernel_launch(void* const* d_in, const int* in_sizes, int n_in,
                              void* d_out, int out_size, void* d_ws, size_t ws_size,
                              hipStream_t stream)
{
    const float* x  = (const float*)d_in[0];
    const float* wq = (const float*)d_in[2];
    const float* bq = (const float*)d_in[3];
    const float* wk = (const float*)d_in[4];
    const float* bk = (const float*)d_in[5];
    const float* wv = (const float*)d_in[6];
    const float* bv = (const float*)d_in[7];
    const float* wo = (const float*)d_in[8];
    const float* bo = (const float*)d_in[9];
    const float* w1 = (const float*)d_in[10];
    const float* b1 = (const float*)d_in[11];
    const float* w2 = (const float*)d_in[12];
    const float* b2 = (const float*)d_in[13];
    const float* g1 = (const float*)d_in[14];
    const float* be1= (const float*)d_in[15];
    const float* g2 = (const float*)d_in[16];
    const float* be2= (const float*)d_in[17];
    float* out = (float*)d_out;

    const size_t MB = 1048576;
    char* w8 = (char*)d_ws;
    unsigned short* wqkvt = (unsigned short*)(w8 + 0);            // 1536x512 bf16
    unsigned short* wot   = (unsigned short*)(w8 + 1572864);      // 512x512
    unsigned short* w1t   = (unsigned short*)(w8 + 2097152);      // 2048x512
    unsigned short* w2t   = (unsigned short*)(w8 + 4194304);      // 512x2048
    float*          bqkv  = (float*)(w8 + 6291456);               // 1536 f32
    unsigned short* qkv   = (unsigned short*)(w8 + 8 * MB);       // 24 MB (later ffn1b)
    unsigned short* ffn1b = qkv;
    unsigned short* xb    = (unsigned short*)(w8 + 40 * MB);      // 8 MB (later ctx)
    unsigned short* ctx   = xb;
    unsigned short* vt    = (unsigned short*)(w8 + 48 * MB);      // 8 MB (later hb)
    unsigned short* hb    = vt;
    float*          pre   = (float*)(w8 + 56 * MB);               // 16 MB
    float*          pre2  = (float*)(w8 + 72 * MB);               // 16 MB (split-K partial)

    const dim3 blk(256);

    // unified preprocessing (1 dispatch)
    prep_kernel<<<dim3(5120), blk, 0, stream>>>(
        x, wq, wk, wv, wo, bq, bk, bv, w1, w2, xb, wqkvt, wot, w1t, w2t, bqkv);

    // qkv = xb @ [wq*SCLQ|wk|wv] + b -> bf16 [M][1536]; V-part written
    // transposed straight into vt (VT=1) — vtrans dispatch eliminated.
    gemm_bf16<2,2,2,4,64,1,0,0,1,1,0><<<dim3(12, 128), blk, 0, stream>>>(
        xb, wqkvt, bqkv, nullptr, qkv, vt, nullptr, 512, 512, 512, 1536);

    // causal flash attention (4-wave k-split, zero-shuffle PV) -> ctx bf16
    attn_mfma<<<dim3(1024), blk, 0, stream>>>(qkv, vt, ctx);

    // pre = x + ctx @ wo + bo (fp32 residual), BK=64 deep-staged
    gemm_bf16<2,2,2,4,64,0,0,1,1,0,0><<<dim3(4, 128), blk, 0, stream>>>(
        ctx, wot, bo, x, pre, nullptr, nullptr, 512, 512, 512, 512);

    // hb = LN(pre) bf16 (residual for FFN carried in bf16 — RNE everywhere)
    ln_kernel<0,1,0><<<dim3(M_ / 4), blk, 0, stream>>>(
        pre, g1, be1, nullptr, hb, nullptr, nullptr, nullptr);

    // ffn1 = relu(hb @ w1 + b1) -> bf16 [M][2048], BK=64 deep-staged
    gemm_bf16<2,2,2,4,64,1,1,0,1,0,0><<<dim3(16, 128), blk, 0, stream>>>(
        hb, w1t, b1, nullptr, ffn1b, nullptr, nullptr, 512, 512, 512, 2048);

    // ffn2 split-K=2: z=0 -> pre (K 0..1023), z=1 -> pre2 (K 1024..2047),
    // raw fp32 partials; grid 1024 doubles residency on this serial shape.
    gemm_bf16<2,2,2,4,64,0,0,0,0,0,1><<<dim3(4, 128, 2), blk, 0, stream>>>(
        ffn1b, w2t, nullptr, nullptr, pre, nullptr, pre2, 1024, 2048, 2048, 512);

    // out = LN(pre + pre2 + b2 + hb)  (split-K combine fused into LN2)
    ln_kernel<1,0,1><<<dim3(M_ / 4), blk, 0, stream>>>(
        pre, g2, be2, out, nullptr, pre2, hb, b2);
}

// Round 15
// 246.765 us; speedup vs baseline: 1.0296x; 1.0296x over previous
//
#include <hip/hip_runtime.h>
#include <math.h>

#define D_   512
#define H_   8
#define DK_  64
#define FF_  2048
#define S_   2048
#define B_   4
#define M_   (B_*S_)     // 8192
#define EPS_ 1e-5f
#define SCLQ 0.1803368801111f   // 0.125 * log2(e): folded into wq/bq at prep

typedef __attribute__((ext_vector_type(8))) short bf16x8;
typedef __attribute__((ext_vector_type(4))) short bf16x4;
typedef __attribute__((ext_vector_type(4))) float f32x4;
typedef __attribute__((ext_vector_type(4))) unsigned int u32x4;

__device__ inline unsigned short f2b(float f) {
    unsigned u = __builtin_bit_cast(unsigned, f);
    unsigned r = (u + 0x7FFFu + ((u >> 16) & 1u)) >> 16;
    return (unsigned short)r;
}
__device__ inline float b2f(unsigned short u) {
    return __builtin_bit_cast(float, (unsigned)u << 16);
}
// pack bf16(p0) low half, bf16(p1) high half — round-to-nearest-even via HW
__device__ inline unsigned packbf(float p0, float p1) {
    unsigned r;
    asm("v_cvt_pk_bf16_f32 %0, %1, %2" : "=v"(r) : "v"(p0), "v"(p1));
    return r;
}

// async 16B global->LDS. LDS dest must be wave-uniform base + lane*16.
__device__ __forceinline__ void async_cp16(const void* g, void* l) {
    __builtin_amdgcn_global_load_lds(
        (const __attribute__((address_space(1))) unsigned int*)g,
        (__attribute__((address_space(3))) unsigned int*)l, 16, 0, 0);
}

// ---------------------------------------------------------------------------
// Unified preprocessing (1 dispatch, 5120 blocks).
// ---------------------------------------------------------------------------
__global__ __launch_bounds__(256)
void prep_kernel(const float* __restrict__ x,
                 const float* __restrict__ wq, const float* __restrict__ wk,
                 const float* __restrict__ wv, const float* __restrict__ wo,
                 const float* __restrict__ bq, const float* __restrict__ bk,
                 const float* __restrict__ bv,
                 const float* __restrict__ w1, const float* __restrict__ w2,
                 unsigned short* __restrict__ xb, unsigned short* __restrict__ wqkvt,
                 unsigned short* __restrict__ wot, unsigned short* __restrict__ w1t,
                 unsigned short* __restrict__ w2t, float* __restrict__ bqkv)
{
    __shared__ float L[32][33];
    const int bid = blockIdx.x;
    const int tid = threadIdx.x;

    if (bid < 2048) {                       // x -> xb
        const int i = (bid * 256 + tid) * 8;
        const float4 a = *(const float4*)(x + i);
        const float4 b = *(const float4*)(x + i + 4);
        bf16x8 v;
        v[0] = (short)f2b(a.x); v[1] = (short)f2b(a.y);
        v[2] = (short)f2b(a.z); v[3] = (short)f2b(a.w);
        v[4] = (short)f2b(b.x); v[5] = (short)f2b(b.y);
        v[6] = (short)f2b(b.z); v[7] = (short)f2b(b.w);
        *(bf16x8*)(xb + i) = v;
        return;
    }

    const float* w; unsigned short* wt; int K, N, k0, n0; float scl = 1.f;
    if (bid < 3072) {
        const int z = (bid - 2048) >> 8;
        const int r = (bid - 2048) & 255;
        n0 = (r & 15) * 32; k0 = (r >> 4) * 32; K = 512; N = 512;
        w  = (z == 0) ? wq : (z == 1) ? wk : (z == 2) ? wv : wo;
        wt = (z < 3) ? (wqkvt + (size_t)z * 512 * 512) : wot;
        if (z == 0) scl = SCLQ;
        if (z < 3 && r == 0) {
            const float* bsrc = (z == 0) ? bq : (z == 1) ? bk : bv;
            const float bscl  = (z == 0) ? SCLQ : 1.f;
            bqkv[z * 512 + tid]       = bsrc[tid] * bscl;
            bqkv[z * 512 + 256 + tid] = bsrc[256 + tid] * bscl;
        }
    } else if (bid < 4096) {
        const int r = bid - 3072;
        n0 = (r & 63) * 32; k0 = (r >> 6) * 32; K = 512; N = 2048;
        w = w1; wt = w1t;
    } else {
        const int r = bid - 4096;
        n0 = (r & 15) * 32; k0 = (r >> 4) * 32; K = 2048; N = 512;
        w = w2; wt = w2t;
    }

    const int xx = tid & 31, y = tid >> 5;
#pragma unroll
    for (int i = 0; i < 4; i++)
        L[y + i * 8][xx] = w[(size_t)(k0 + y + i * 8) * N + n0 + xx] * scl;
    __syncthreads();
#pragma unroll
    for (int i = 0; i < 4; i++)
        wt[(size_t)(n0 + y + i * 8) * K + k0 + xx] = f2b(L[xx][y + i * 8]);
}

// ---------------------------------------------------------------------------
// bf16 MFMA GEMM, double-buffered (prefetch + partial vmcnt + raw s_barrier).
// BK: K-depth staged per barrier-pair. BK=64's 128B LDS rows are XOR-swizzled
// (source-side) against bank conflicts. Tile 64x128 everywhere (r11: 128x128
// at BK=64 = 64KB LDS = 2 blocks/CU occupancy cliff, 255->263; don't re-raise).
// XCD-aware block swizzle (T1): remap lin -> (lin%8)*(nwg/8) + lin/8 so each
// XCD L2 gets a contiguous chunk of complete A-panel groups (r2: ffn2 FETCH
// 78MB vs 34MB ideal from round-robin panel re-fetch). nwg%8==0 all grids.
// Split-K on ffn2 was measured NEUTRAL (r14: 254.1 vs 253.3) — partial-buffer
// traffic offsets the occupancy gain; dropped.
// RESADD: 0 none, 1 fp32 residual, 2 bf16 residual (C-layout indexed).
// In-place RES==Cv is safe: each idx is read-then-written by one thread.
// VT: cols >= 1024 are the V-projection — written TRANSPOSED into
// vtout[(b*512 + (col-1024))][s] as one short4 (4 consecutive s).
// ---------------------------------------------------------------------------
template<int WR, int WC, int MT, int NT, int BK, int OUTB, int RELU, int RESADD, int HASBIAS, int VT>
__global__ __launch_bounds__(256)
void gemm_bf16(const unsigned short* __restrict__ A, const unsigned short* __restrict__ Bt,
               const float* __restrict__ bias, const void* __restrict__ RES,
               void* __restrict__ Cv, unsigned short* __restrict__ vtout,
               int K, int lda, int ldb, int ldc)
{
    constexpr int BM  = WR * MT * 16;
    constexpr int BN  = WC * NT * 16;
    constexpr int CPR = BK / 8;              // 16B chunks per LDS row
    constexpr int CA  = BM * BK / (256 * 8);
    constexpr int CB  = BN * BK / (256 * 8);
    __shared__ unsigned short As[2][BM * BK];
    __shared__ unsigned short Bs[2][BN * BK];

    const int tid  = threadIdx.x;
    const int lane = tid & 63;
    const int w    = tid >> 6;
    const int wr   = w / WC, wc = w % WC;
    const int quad = lane >> 4;
    const int l15  = lane & 15;

    // XCD-aware swizzle: lin%8 = XCD, give each a contiguous work chunk.
    const int nwg = gridDim.x * gridDim.y;
    const int lin = blockIdx.y * gridDim.x + blockIdx.x;
    const int swz = (lin & 7) * (nwg >> 3) + (lin >> 3);
    const int n0  = (swz % gridDim.x) * BN;
    const int m0  = (swz / gridDim.x) * BM;

    f32x4 acc[MT][NT];
#pragma unroll
    for (int i = 0; i < MT; i++)
#pragma unroll
        for (int j = 0; j < NT; j++) acc[i][j] = (f32x4){0.f, 0.f, 0.f, 0.f};

    auto stage = [&](int k0, int bufi) {
#pragma unroll
        for (int i = 0; i < CA; i++) {
            const int c   = tid + i * 256;
            const int row = c / CPR;
            int l = c % CPR;
            if (BK == 64) l ^= (row & 7);    // source-side swizzle, LDS linear
            async_cp16(&A[(size_t)(m0 + row) * lda + k0 + l * 8], &As[bufi][c * 8]);
        }
#pragma unroll
        for (int i = 0; i < CB; i++) {
            const int c   = tid + i * 256;
            const int row = c / CPR;
            int l = c % CPR;
            if (BK == 64) l ^= (row & 7);
            async_cp16(&Bt[(size_t)(n0 + row) * ldb + k0 + l * 8], &Bs[bufi][c * 8]);
        }
    };

    stage(0, 0);
    const int niter = K / BK;
    for (int ii = 0; ii < niter; ii++) {
        const int knext = (ii + 1 < niter) ? (ii + 1) * BK : 0;
        stage(knext, (ii + 1) & 1);
        __builtin_amdgcn_s_waitcnt(0x0f70 | (CA + CB));
        __builtin_amdgcn_s_barrier();

        const unsigned short* Ac = &As[ii & 1][0];
        const unsigned short* Bc = &Bs[ii & 1][0];
#pragma unroll
        for (int ks = 0; ks < BK / 32; ks++) {
            bf16x8 af[MT], bfr[NT];
#pragma unroll
            for (int t = 0; t < MT; t++) {
                const int r = wr * MT * 16 + t * 16 + l15;
                int ch = (ks << 2) | quad;
                if (BK == 64) ch ^= (r & 7);
                af[t] = *(const bf16x8*)&Ac[r * BK + ch * 8];
            }
#pragma unroll
            for (int t = 0; t < NT; t++) {
                const int r = wc * NT * 16 + t * 16 + l15;
                int ch = (ks << 2) | quad;
                if (BK == 64) ch ^= (r & 7);
                bfr[t] = *(const bf16x8*)&Bc[r * BK + ch * 8];
            }
#pragma unroll
            for (int mt = 0; mt < MT; mt++)
#pragma unroll
                for (int nt = 0; nt < NT; nt++)
                    acc[mt][nt] = __builtin_amdgcn_mfma_f32_16x16x32_bf16(
                        af[mt], bfr[nt], acc[mt][nt], 0, 0, 0);
        }
        __builtin_amdgcn_s_barrier();
    }

    // epilogue: C/D layout col=lane&15, row=quad*4+reg
#pragma unroll
    for (int mt = 0; mt < MT; mt++) {
        const int rowb = m0 + wr * MT * 16 + mt * 16 + quad * 4;
#pragma unroll
        for (int nt = 0; nt < NT; nt++) {
            const int col = n0 + wc * NT * 16 + nt * 16 + l15;
            const float bv = HASBIAS ? bias[col] : 0.f;
            if (VT && col >= 1024) {
                // V-projection: transposed bf16 write, one short4 (4 s-values)
                short4 sv;
                sv.x = (short)f2b(acc[mt][nt][0] + bv);
                sv.y = (short)f2b(acc[mt][nt][1] + bv);
                sv.z = (short)f2b(acc[mt][nt][2] + bv);
                sv.w = (short)f2b(acc[mt][nt][3] + bv);
                const int bb = rowb >> 11;           // batch (row/2048); uniform per block
                *(short4*)&vtout[(size_t)(bb * 512 + (col - 1024)) * S_ + (rowb & 2047)] = sv;
            } else {
#pragma unroll
                for (int r = 0; r < 4; r++) {
                    const size_t idx = (size_t)(rowb + r) * ldc + col;
                    float v = acc[mt][nt][r] + bv;
                    if (RESADD == 1) v += ((const float*)RES)[idx];
                    if (RESADD == 2) v += b2f(((const unsigned short*)RES)[idx]);
                    if (RELU)   v = fmaxf(v, 0.f);
                    if (OUTB) ((unsigned short*)Cv)[idx] = f2b(v);
                    else      ((float*)Cv)[idx] = v;
                }
            }
        }
    }
}

// ---------------------------------------------------------------------------
// Causal flash attention, K-SPLIT register-P, ZERO-SHUFFLE PV.
// BQ=64, KB=64, grid 1024, 4 waves/block. Wave w = (qh=w>>1, kh=w&1):
// 32 queries x 32 keys, 2 q-tiles sharing every K/V ds_read.
// Softmax->PV handoff with NO transpose: QK^T (S^T trick) leaves lane l with
// P[k=quad*4+r][q=l15]; the A-fragment of v_mfma_f32_16x16x16_bf16 is
// A[m=l15][k=quad*4+j] — the SAME lane mapping (m=q, j=r). PV runs as
// 2x K=16 MFMAs per 32-k chunk with the packed exp2 output used directly.
// Work balance: CU hosts bids {c,c+256,c+512,c+768}; qb(g) makes every
// quadruple sum to 62 tile-iters. Same-bh blocks are stride-32 apart
// (32%8==0) -> already co-located per XCD; no swizzle needed here.
// ---------------------------------------------------------------------------
__global__ __launch_bounds__(256, 4)
void attn_mfma(const unsigned short* __restrict__ qkv,
               const unsigned short* __restrict__ vt,
               unsigned short* __restrict__ ctx)
{
    // Arena (32 KB): [0..8191] Ks dbuf [kr][d] chunk^=(kr&7);
    // [8192..16383] Vs dbuf [dk][kr] chunk^=(dk&7).
    // First 22.5 KB reused as f32 reduction scratch at the end.
    __shared__ unsigned short Arena[16384];

    const int tid  = threadIdx.x;
    const int lane = tid & 63;
    const int w    = tid >> 6;                  // 0..3
    const int quad = lane >> 4;
    const int l15  = lane & 15;
    const int bid  = blockIdx.x;
    const int g    = bid >> 5;
    // CU-balanced qb permutation (bijective over g=0..31)
    const int qb   = (g < 8) ? 31 - g : (g < 16) ? g + 8 : (g < 24) ? 31 - g : g - 24;
    const int bh   = bid & 31;
    const int b    = bh >> 3, hh = bh & 7;
    const int kh   = w & 1;                     // k-chunk (32 keys)
    const int qh   = w >> 1;                    // q-half (32 queries)

    const unsigned short* qbase = qkv + (size_t)(b * S_) * 1536 + hh * 64;
    const unsigned short* kbase = qbase + 512;
    const unsigned short* vtb   = vt + (size_t)bh * 64 * S_;

    bf16x4 ones4;
#pragma unroll
    for (int j = 0; j < 4; j++) ones4[j] = (short)0x3F80;

    auto stage = [&](int kb, int bufi) {
        unsigned short* kd = &Arena[bufi * 4096];
        unsigned short* vd = &Arena[8192 + bufi * 4096];
#pragma unroll
        for (int i = 0; i < 2; i++) {
            const int c = tid + i * 256;
            const int row = c >> 3;
            const int l = (c & 7) ^ (row & 7);
            async_cp16(kbase + (size_t)(kb * 64 + row) * 1536 + l * 8, kd + c * 8);
            async_cp16(vtb + (size_t)row * S_ + kb * 64 + l * 8, vd + c * 8);
        }
    };

    // Q fragments: 2 q-tiles x 2 kc (d chunks)
    bf16x8 qf[2][2];
#pragma unroll
    for (int qt = 0; qt < 2; qt++) {
        const unsigned short* qr = qbase + (size_t)(qb * 64 + qh * 32 + qt * 16 + l15) * 1536;
        qf[qt][0] = *(const bf16x8*)(qr + quad * 8);
        qf[qt][1] = *(const bf16x8*)(qr + 32 + quad * 8);
    }

    f32x4 Oacc[2][5];                           // [qt][0..3]=O dk-tiles, [4]=row-sum
#pragma unroll
    for (int qt = 0; qt < 2; qt++)
#pragma unroll
        for (int i = 0; i < 5; i++) Oacc[qt][i] = (f32x4){0.f, 0.f, 0.f, 0.f};

    stage(0, 0);

    // V b64 fragment address (shorts): per (kt,nt), kr = kh*32+kt*16+quad*4
    const int vch0 = (kh * 4 + (quad >> 1));    // ^(l15&7) applied per read
    const int vsub = (quad & 1) * 4;

    // ---- main loop (kb < qb): no masking
    for (int kb = 0; kb < qb; kb++) {
        stage(kb + 1, (kb + 1) & 1);
        __builtin_amdgcn_s_waitcnt(0x0F74);     // vmcnt(4): current tile done
        __builtin_amdgcn_s_barrier();
        const unsigned short* Kc = &Arena[(kb & 1) * 4096];
        const unsigned short* Vc = &Arena[8192 + (kb & 1) * 4096];

        f32x4 st[2][2];                         // [qt][kt]
#pragma unroll
        for (int qt = 0; qt < 2; qt++)
#pragma unroll
            for (int kt = 0; kt < 2; kt++) st[qt][kt] = (f32x4){0.f, 0.f, 0.f, 0.f};
#pragma unroll
        for (int kc = 0; kc < 2; kc++) {
            const int phys = (kc * 4 + quad) ^ (l15 & 7);
            const bf16x8 kf0 = *(const bf16x8*)&Kc[(kh * 32 + l15) * 64 + phys * 8];
            const bf16x8 kf1 = *(const bf16x8*)&Kc[(kh * 32 + 16 + l15) * 64 + phys * 8];
#pragma unroll
            for (int qt = 0; qt < 2; qt++) {
                st[qt][0] = __builtin_amdgcn_mfma_f32_16x16x32_bf16(kf0, qf[qt][kc], st[qt][0], 0, 0, 0);
                st[qt][1] = __builtin_amdgcn_mfma_f32_16x16x32_bf16(kf1, qf[qt][kc], st[qt][1], 0, 0, 0);
            }
        }

        // V fragments: b64 per (kt,nt)
        bf16x4 vf[2][4];
#pragma unroll
        for (int kt = 0; kt < 2; kt++)
#pragma unroll
            for (int nt = 0; nt < 4; nt++)
                vf[kt][nt] = *(const bf16x4*)&Vc[(nt * 16 + l15) * 64 +
                    (((vch0 + kt * 2) ^ (l15 & 7)) << 3) + vsub];

        // P directly in registers as K=16 A-fragments
#pragma unroll
        for (int qt = 0; qt < 2; qt++) {
#pragma unroll
            for (int kt = 0; kt < 2; kt++) {
                uint2 aw;
                aw.x = packbf(exp2f(st[qt][kt][0]), exp2f(st[qt][kt][1]));
                aw.y = packbf(exp2f(st[qt][kt][2]), exp2f(st[qt][kt][3]));
                const bf16x4 af = __builtin_bit_cast(bf16x4, aw);
#pragma unroll
                for (int nt = 0; nt < 4; nt++)
                    Oacc[qt][nt] = __builtin_amdgcn_mfma_f32_16x16x16bf16_1k(
                        af, vf[kt][nt], Oacc[qt][nt], 0, 0, 0);
                Oacc[qt][4] = __builtin_amdgcn_mfma_f32_16x16x16bf16_1k(
                    af, ones4, Oacc[qt][4], 0, 0, 0);
            }
        }
        __builtin_amdgcn_s_barrier();           // reads done before re-stage
    }

    // ---- peeled diagonal iteration (kb == qb)
    {
        stage(0, (qb + 1) & 1);                 // dummy prefetch (vmcnt uniform)
        __builtin_amdgcn_s_waitcnt(0x0F74);
        __builtin_amdgcn_s_barrier();
        const unsigned short* Kc = &Arena[(qb & 1) * 4096];
        const unsigned short* Vc = &Arena[8192 + (qb & 1) * 4096];

        const bool skipDiag = (kh == 1 && qh == 0);   // k 32..63 > q 0..31: all masked
        const bool fullDiag = (kh == 0 && qh == 1);   // k 0..31 < q 32..63: no mask

        if (!skipDiag) {
            f32x4 st[2][2];
#pragma unroll
            for (int qt = 0; qt < 2; qt++)
#pragma unroll
                for (int kt = 0; kt < 2; kt++) st[qt][kt] = (f32x4){0.f, 0.f, 0.f, 0.f};
#pragma unroll
            for (int kc = 0; kc < 2; kc++) {
                const int phys = (kc * 4 + quad) ^ (l15 & 7);
                const bf16x8 kf0 = *(const bf16x8*)&Kc[(kh * 32 + l15) * 64 + phys * 8];
                const bf16x8 kf1 = *(const bf16x8*)&Kc[(kh * 32 + 16 + l15) * 64 + phys * 8];
#pragma unroll
                for (int qt = 0; qt < 2; qt++) {
                    st[qt][0] = __builtin_amdgcn_mfma_f32_16x16x32_bf16(kf0, qf[qt][kc], st[qt][0], 0, 0, 0);
                    st[qt][1] = __builtin_amdgcn_mfma_f32_16x16x32_bf16(kf1, qf[qt][kc], st[qt][1], 0, 0, 0);
                }
            }

            // per-(qt,kt) tile class: fullDiag -> all full;
            // else (kh==qh): (0,0) tri, (0,1) zero, (1,0) full, (1,1) tri.
            bf16x4 af[2][2];
            if (fullDiag) {
#pragma unroll
                for (int qt = 0; qt < 2; qt++)
#pragma unroll
                    for (int kt = 0; kt < 2; kt++) {
                        uint2 aw;
                        aw.x = packbf(exp2f(st[qt][kt][0]), exp2f(st[qt][kt][1]));
                        aw.y = packbf(exp2f(st[qt][kt][2]), exp2f(st[qt][kt][3]));
                        af[qt][kt] = __builtin_bit_cast(bf16x4, aw);
                    }
            } else {
                float p[4];
                uint2 aw;
#pragma unroll
                for (int r = 0; r < 4; r++)
                    p[r] = (quad * 4 + r > l15) ? 0.f : exp2f(st[0][0][r]);
                aw.x = packbf(p[0], p[1]); aw.y = packbf(p[2], p[3]);
                af[0][0] = __builtin_bit_cast(bf16x4, aw);
                af[0][1] = (bf16x4){0, 0, 0, 0};
                aw.x = packbf(exp2f(st[1][0][0]), exp2f(st[1][0][1]));
                aw.y = packbf(exp2f(st[1][0][2]), exp2f(st[1][0][3]));
                af[1][0] = __builtin_bit_cast(bf16x4, aw);
#pragma unroll
                for (int r = 0; r < 4; r++)
                    p[r] = (quad * 4 + r > l15) ? 0.f : exp2f(st[1][1][r]);
                aw.x = packbf(p[0], p[1]); aw.y = packbf(p[2], p[3]);
                af[1][1] = __builtin_bit_cast(bf16x4, aw);
            }

            bf16x4 vf[2][4];
#pragma unroll
            for (int kt = 0; kt < 2; kt++)
#pragma unroll
                for (int nt = 0; nt < 4; nt++)
                    vf[kt][nt] = *(const bf16x4*)&Vc[(nt * 16 + l15) * 64 +
                        (((vch0 + kt * 2) ^ (l15 & 7)) << 3) + vsub];

#pragma unroll
            for (int qt = 0; qt < 2; qt++)
#pragma unroll
                for (int kt = 0; kt < 2; kt++) {
#pragma unroll
                    for (int nt = 0; nt < 4; nt++)
                        Oacc[qt][nt] = __builtin_amdgcn_mfma_f32_16x16x16bf16_1k(
                            af[qt][kt], vf[kt][nt], Oacc[qt][nt], 0, 0, 0);
                    Oacc[qt][4] = __builtin_amdgcn_mfma_f32_16x16x16bf16_1k(
                        af[qt][kt], ones4, Oacc[qt][4], 0, 0, 0);
                }
        }
    }

    // ---- cross-wave reduction (kh=1 partials -> kh=0), then write ctx
    __syncthreads();
    float* red = (float*)&Arena[0];             // 2 regions x 64 lanes x 44 floats = 22.5 KB
    const int rbase = (qh * 64 + lane) * 44;
    if (kh) {
#pragma unroll
        for (int qt = 0; qt < 2; qt++)
#pragma unroll
            for (int i = 0; i < 5; i++)
                *(f32x4*)&red[rbase + (qt * 5 + i) * 4] = Oacc[qt][i];
    }
    __syncthreads();
    if (!kh) {
#pragma unroll
        for (int qt = 0; qt < 2; qt++)
#pragma unroll
            for (int i = 0; i < 5; i++)
                Oacc[qt][i] += *(const f32x4*)&red[rbase + (qt * 5 + i) * 4];

        unsigned short* cb = ctx + (size_t)(b * S_) * 512 + hh * 64;
#pragma unroll
        for (int qt = 0; qt < 2; qt++) {
            const int orow = qb * 64 + qh * 32 + qt * 16 + quad * 4;
#pragma unroll
            for (int r = 0; r < 4; r++) {
                const float inv = 1.f / Oacc[qt][4][r];
#pragma unroll
                for (int nt = 0; nt < 4; nt++)
                    cb[(size_t)(orow + r) * 512 + nt * 16 + l15] = f2b(Oacc[qt][nt][r] * inv);
            }
        }
    }
}

// ---------------------------------------------------------------------------
// LayerNorm: WF -> fp32 out, WB -> bf16 out. 1 wave/row.
// In-place (s == out) is safe: each thread reads its row slice to registers
// before any write.
// ---------------------------------------------------------------------------
template<int WF, int WB>
__global__ __launch_bounds__(256)
void ln_kernel(const float* __restrict__ s, const float* __restrict__ g,
               const float* __restrict__ be, float* __restrict__ out,
               unsigned short* __restrict__ outb)
{
    const int wave = threadIdx.x >> 6;
    const int lane = threadIdx.x & 63;
    const int row  = blockIdx.x * 4 + wave;
    const float* ps = s + (size_t)row * D_;
    const int c0 = lane * 4;

    float v[8];
    {
        const float4 a0 = *(const float4*)(ps + c0);
        const float4 a1 = *(const float4*)(ps + c0 + 256);
        v[0] = a0.x; v[1] = a0.y; v[2] = a0.z; v[3] = a0.w;
        v[4] = a1.x; v[5] = a1.y; v[6] = a1.z; v[7] = a1.w;
    }

    float sum = 0.f;
#pragma unroll
    for (int i = 0; i < 8; i++) sum += v[i];
#pragma unroll
    for (int m = 1; m < 64; m <<= 1) sum += __shfl_xor(sum, m);
    const float mu = sum * (1.f / D_);

    float sq = 0.f;
#pragma unroll
    for (int i = 0; i < 8; i++) { const float d = v[i] - mu; sq += d * d; }
#pragma unroll
    for (int m = 1; m < 64; m <<= 1) sq += __shfl_xor(sq, m);
    const float rstd = rsqrtf(sq * (1.f / D_) + EPS_);

    const float4 g0 = *(const float4*)(g + c0);
    const float4 b0 = *(const float4*)(be + c0);
    const float4 g1 = *(const float4*)(g + c0 + 256);
    const float4 b1 = *(const float4*)(be + c0 + 256);

    float o[8];
    o[0] = (v[0] - mu) * rstd * g0.x + b0.x;
    o[1] = (v[1] - mu) * rstd * g0.y + b0.y;
    o[2] = (v[2] - mu) * rstd * g0.z + b0.z;
    o[3] = (v[3] - mu) * rstd * g0.w + b0.w;
    o[4] = (v[4] - mu) * rstd * g1.x + b1.x;
    o[5] = (v[5] - mu) * rstd * g1.y + b1.y;
    o[6] = (v[6] - mu) * rstd * g1.z + b1.z;
    o[7] = (v[7] - mu) * rstd * g1.w + b1.w;

    if (WF) {
        *(float4*)(out + (size_t)row * D_ + c0)       = *(float4*)&o[0];
        *(float4*)(out + (size_t)row * D_ + c0 + 256) = *(float4*)&o[4];
    }
    if (WB) {
        short4 vb0 = (short4){(short)f2b(o[0]), (short)f2b(o[1]), (short)f2b(o[2]), (short)f2b(o[3])};
        short4 vb1 = (short4){(short)f2b(o[4]), (short)f2b(o[5]), (short)f2b(o[6]), (short)f2b(o[7])};
        *(short4*)(outb + (size_t)row * D_ + c0)       = vb0;
        *(short4*)(outb + (size_t)row * D_ + c0 + 256) = vb1;
    }
}

// ---------------------------------------------------------------------------
extern "C" void kernel_launch(void* const* d_in, const int* in_sizes, int n_in,
                              void* d_out, int out_size, void* d_ws, size_t ws_size,
                              hipStream_t stream)
{
    const float* x  = (const float*)d_in[0];
    const float* wq = (const float*)d_in[2];
    const float* bq = (const float*)d_in[3];
    const float* wk = (const float*)d_in[4];
    const float* bk = (const float*)d_in[5];
    const float* wv = (const float*)d_in[6];
    const float* bv = (const float*)d_in[7];
    const float* wo = (const float*)d_in[8];
    const float* bo = (const float*)d_in[9];
    const float* w1 = (const float*)d_in[10];
    const float* b1 = (const float*)d_in[11];
    const float* w2 = (const float*)d_in[12];
    const float* b2 = (const float*)d_in[13];
    const float* g1 = (const float*)d_in[14];
    const float* be1= (const float*)d_in[15];
    const float* g2 = (const float*)d_in[16];
    const float* be2= (const float*)d_in[17];
    float* out = (float*)d_out;

    const size_t MB = 1048576;
    char* w8 = (char*)d_ws;
    unsigned short* wqkvt = (unsigned short*)(w8 + 0);            // 1536x512 bf16
    unsigned short* wot   = (unsigned short*)(w8 + 1572864);      // 512x512
    unsigned short* w1t   = (unsigned short*)(w8 + 2097152);      // 2048x512
    unsigned short* w2t   = (unsigned short*)(w8 + 4194304);      // 512x2048
    float*          bqkv  = (float*)(w8 + 6291456);               // 1536 f32
    unsigned short* qkv   = (unsigned short*)(w8 + 8 * MB);       // 24 MB (later ffn1b)
    unsigned short* ffn1b = qkv;
    unsigned short* xb    = (unsigned short*)(w8 + 40 * MB);      // 8 MB (later ctx)
    unsigned short* ctx   = xb;
    unsigned short* vt    = (unsigned short*)(w8 + 48 * MB);      // 8 MB (later hb)
    unsigned short* hb    = vt;
    float*          pre   = (float*)(w8 + 56 * MB);               // 16 MB

    const dim3 blk(256);

    // unified preprocessing (1 dispatch)
    prep_kernel<<<dim3(5120), blk, 0, stream>>>(
        x, wq, wk, wv, wo, bq, bk, bv, w1, w2, xb, wqkvt, wot, w1t, w2t, bqkv);

    // qkv = xb @ [wq*SCLQ|wk|wv] + b -> bf16 [M][1536]; V-part written
    // transposed straight into vt (VT=1) — vtrans dispatch eliminated.
    gemm_bf16<2,2,2,4,64,1,0,0,1,1><<<dim3(12, 128), blk, 0, stream>>>(
        xb, wqkvt, bqkv, nullptr, qkv, vt, 512, 512, 512, 1536);

    // causal flash attention (4-wave k-split, zero-shuffle PV) -> ctx bf16
    attn_mfma<<<dim3(1024), blk, 0, stream>>>(qkv, vt, ctx);

    // pre = x + ctx @ wo + bo (fp32 residual), BK=64 deep-staged
    gemm_bf16<2,2,2,4,64,0,0,1,1,0><<<dim3(4, 128), blk, 0, stream>>>(
        ctx, wot, bo, x, pre, nullptr, 512, 512, 512, 512);

    // hb = LN(pre) bf16 (residual for FFN carried in bf16 — RNE everywhere)
    ln_kernel<0,1><<<dim3(M_ / 4), blk, 0, stream>>>(pre, g1, be1, nullptr, hb);

    // ffn1 = relu(hb @ w1 + b1) -> bf16 [M][2048], BK=64 deep-staged
    gemm_bf16<2,2,2,4,64,1,1,0,1,0><<<dim3(16, 128), blk, 0, stream>>>(
        hb, w1t, b1, nullptr, ffn1b, nullptr, 512, 512, 512, 2048);

    // pre = hb + ffn1 @ w2 + b2 (bf16 residual), BK=64 deep-staged
    gemm_bf16<2,2,2,4,64,0,0,2,1,0><<<dim3(4, 128), blk, 0, stream>>>(
        ffn1b, w2t, b2, hb, pre, nullptr, 2048, 2048, 2048, 512);

    // out = LN(pre)
    ln_kernel<1,0><<<dim3(M_ / 4), blk, 0, stream>>>(pre, g2, be2, out, nullptr);
}

// Round 16
// 242.945 us; speedup vs baseline: 1.0458x; 1.0157x over previous
//
#include <hip/hip_runtime.h>
#include <math.h>

#define D_   512
#define H_   8
#define DK_  64
#define FF_  2048
#define S_   2048
#define B_   4
#define M_   (B_*S_)     // 8192
#define EPS_ 1e-5f
#define SCLQ 0.1803368801111f   // 0.125 * log2(e): folded into wq/bq at prep

typedef __attribute__((ext_vector_type(8))) short bf16x8;
typedef __attribute__((ext_vector_type(4))) short bf16x4;
typedef __attribute__((ext_vector_type(4))) float f32x4;
typedef __attribute__((ext_vector_type(4))) unsigned int u32x4;

__device__ inline unsigned short f2b(float f) {
    unsigned u = __builtin_bit_cast(unsigned, f);
    unsigned r = (u + 0x7FFFu + ((u >> 16) & 1u)) >> 16;
    return (unsigned short)r;
}
__device__ inline float b2f(unsigned short u) {
    return __builtin_bit_cast(float, (unsigned)u << 16);
}
// pack bf16(p0) low half, bf16(p1) high half — round-to-nearest-even via HW
__device__ inline unsigned packbf(float p0, float p1) {
    unsigned r;
    asm("v_cvt_pk_bf16_f32 %0, %1, %2" : "=v"(r) : "v"(p0), "v"(p1));
    return r;
}

// async 16B global->LDS. LDS dest must be wave-uniform base + lane*16.
__device__ __forceinline__ void async_cp16(const void* g, void* l) {
    __builtin_amdgcn_global_load_lds(
        (const __attribute__((address_space(1))) unsigned int*)g,
        (__attribute__((address_space(3))) unsigned int*)l, 16, 0, 0);
}

// ---------------------------------------------------------------------------
// Unified preprocessing (1 dispatch, 5120 blocks).
// ---------------------------------------------------------------------------
__global__ __launch_bounds__(256)
void prep_kernel(const float* __restrict__ x,
                 const float* __restrict__ wq, const float* __restrict__ wk,
                 const float* __restrict__ wv, const float* __restrict__ wo,
                 const float* __restrict__ bq, const float* __restrict__ bk,
                 const float* __restrict__ bv,
                 const float* __restrict__ w1, const float* __restrict__ w2,
                 unsigned short* __restrict__ xb, unsigned short* __restrict__ wqkvt,
                 unsigned short* __restrict__ wot, unsigned short* __restrict__ w1t,
                 unsigned short* __restrict__ w2t, float* __restrict__ bqkv)
{
    __shared__ float L[32][33];
    const int bid = blockIdx.x;
    const int tid = threadIdx.x;

    if (bid < 2048) {                       // x -> xb
        const int i = (bid * 256 + tid) * 8;
        const float4 a = *(const float4*)(x + i);
        const float4 b = *(const float4*)(x + i + 4);
        bf16x8 v;
        v[0] = (short)f2b(a.x); v[1] = (short)f2b(a.y);
        v[2] = (short)f2b(a.z); v[3] = (short)f2b(a.w);
        v[4] = (short)f2b(b.x); v[5] = (short)f2b(b.y);
        v[6] = (short)f2b(b.z); v[7] = (short)f2b(b.w);
        *(bf16x8*)(xb + i) = v;
        return;
    }

    const float* w; unsigned short* wt; int K, N, k0, n0; float scl = 1.f;
    if (bid < 3072) {
        const int z = (bid - 2048) >> 8;
        const int r = (bid - 2048) & 255;
        n0 = (r & 15) * 32; k0 = (r >> 4) * 32; K = 512; N = 512;
        w  = (z == 0) ? wq : (z == 1) ? wk : (z == 2) ? wv : wo;
        wt = (z < 3) ? (wqkvt + (size_t)z * 512 * 512) : wot;
        if (z == 0) scl = SCLQ;
        if (z < 3 && r == 0) {
            const float* bsrc = (z == 0) ? bq : (z == 1) ? bk : bv;
            const float bscl  = (z == 0) ? SCLQ : 1.f;
            bqkv[z * 512 + tid]       = bsrc[tid] * bscl;
            bqkv[z * 512 + 256 + tid] = bsrc[256 + tid] * bscl;
        }
    } else if (bid < 4096) {
        const int r = bid - 3072;
        n0 = (r & 63) * 32; k0 = (r >> 6) * 32; K = 512; N = 2048;
        w = w1; wt = w1t;
    } else {
        const int r = bid - 4096;
        n0 = (r & 15) * 32; k0 = (r >> 4) * 32; K = 2048; N = 512;
        w = w2; wt = w2t;
    }

    const int xx = tid & 31, y = tid >> 5;
#pragma unroll
    for (int i = 0; i < 4; i++)
        L[y + i * 8][xx] = w[(size_t)(k0 + y + i * 8) * N + n0 + xx] * scl;
    __syncthreads();
#pragma unroll
    for (int i = 0; i < 4; i++)
        wt[(size_t)(n0 + y + i * 8) * K + k0 + xx] = f2b(L[xx][y + i * 8]);
}

// ---------------------------------------------------------------------------
// bf16 MFMA GEMM, double-buffered (prefetch + partial vmcnt + raw s_barrier).
// BK: K-depth staged per barrier-pair. BK=64's 128B LDS rows are XOR-swizzled
// (source-side) against bank conflicts. Tile 64x128 everywhere (r11: 128x128
// at BK=64 = 64KB LDS = 2 blocks/CU occupancy cliff, 255->263; don't re-raise).
// XCD-aware block swizzle (T1): remap lin -> (lin%8)*(nwg/8) + lin/8 so each
// XCD L2 gets a contiguous chunk of complete A-panel groups (r2: ffn2 FETCH
// 78MB vs 34MB ideal from round-robin panel re-fetch). nwg%8==0 all grids.
// Split-K on ffn2 was measured NEUTRAL (r14: 254.1 vs 253.3) — dropped.
// RESADD: 0 none, 1 fp32 residual, 2 bf16 residual (C-layout indexed).
// In-place RES==Cv is safe: each idx is read-then-written by one thread.
// VT: cols >= 1024 are the V-projection — written TRANSPOSED into
// vtout[(b*512 + (col-1024))][s] as one short4 (4 consecutive s).
// Pre-LN intermediates are stored bf16 (OUTB=1): quantization happens AFTER
// full fp32 accum + residual, just before a LayerNorm (~2^-9 rel) — saves
// 16MB/use of fp32 round-trip (r15->r16 traffic cut).
// ---------------------------------------------------------------------------
template<int WR, int WC, int MT, int NT, int BK, int OUTB, int RELU, int RESADD, int HASBIAS, int VT>
__global__ __launch_bounds__(256)
void gemm_bf16(const unsigned short* __restrict__ A, const unsigned short* __restrict__ Bt,
               const float* __restrict__ bias, const void* __restrict__ RES,
               void* __restrict__ Cv, unsigned short* __restrict__ vtout,
               int K, int lda, int ldb, int ldc)
{
    constexpr int BM  = WR * MT * 16;
    constexpr int BN  = WC * NT * 16;
    constexpr int CPR = BK / 8;              // 16B chunks per LDS row
    constexpr int CA  = BM * BK / (256 * 8);
    constexpr int CB  = BN * BK / (256 * 8);
    __shared__ unsigned short As[2][BM * BK];
    __shared__ unsigned short Bs[2][BN * BK];

    const int tid  = threadIdx.x;
    const int lane = tid & 63;
    const int w    = tid >> 6;
    const int wr   = w / WC, wc = w % WC;
    const int quad = lane >> 4;
    const int l15  = lane & 15;

    // XCD-aware swizzle: lin%8 = XCD, give each a contiguous work chunk.
    const int nwg = gridDim.x * gridDim.y;
    const int lin = blockIdx.y * gridDim.x + blockIdx.x;
    const int swz = (lin & 7) * (nwg >> 3) + (lin >> 3);
    const int n0  = (swz % gridDim.x) * BN;
    const int m0  = (swz / gridDim.x) * BM;

    f32x4 acc[MT][NT];
#pragma unroll
    for (int i = 0; i < MT; i++)
#pragma unroll
        for (int j = 0; j < NT; j++) acc[i][j] = (f32x4){0.f, 0.f, 0.f, 0.f};

    auto stage = [&](int k0, int bufi) {
#pragma unroll
        for (int i = 0; i < CA; i++) {
            const int c   = tid + i * 256;
            const int row = c / CPR;
            int l = c % CPR;
            if (BK == 64) l ^= (row & 7);    // source-side swizzle, LDS linear
            async_cp16(&A[(size_t)(m0 + row) * lda + k0 + l * 8], &As[bufi][c * 8]);
        }
#pragma unroll
        for (int i = 0; i < CB; i++) {
            const int c   = tid + i * 256;
            const int row = c / CPR;
            int l = c % CPR;
            if (BK == 64) l ^= (row & 7);
            async_cp16(&Bt[(size_t)(n0 + row) * ldb + k0 + l * 8], &Bs[bufi][c * 8]);
        }
    };

    stage(0, 0);
    const int niter = K / BK;
    for (int ii = 0; ii < niter; ii++) {
        const int knext = (ii + 1 < niter) ? (ii + 1) * BK : 0;
        stage(knext, (ii + 1) & 1);
        __builtin_amdgcn_s_waitcnt(0x0f70 | (CA + CB));
        __builtin_amdgcn_s_barrier();

        const unsigned short* Ac = &As[ii & 1][0];
        const unsigned short* Bc = &Bs[ii & 1][0];
#pragma unroll
        for (int ks = 0; ks < BK / 32; ks++) {
            bf16x8 af[MT], bfr[NT];
#pragma unroll
            for (int t = 0; t < MT; t++) {
                const int r = wr * MT * 16 + t * 16 + l15;
                int ch = (ks << 2) | quad;
                if (BK == 64) ch ^= (r & 7);
                af[t] = *(const bf16x8*)&Ac[r * BK + ch * 8];
            }
#pragma unroll
            for (int t = 0; t < NT; t++) {
                const int r = wc * NT * 16 + t * 16 + l15;
                int ch = (ks << 2) | quad;
                if (BK == 64) ch ^= (r & 7);
                bfr[t] = *(const bf16x8*)&Bc[r * BK + ch * 8];
            }
#pragma unroll
            for (int mt = 0; mt < MT; mt++)
#pragma unroll
                for (int nt = 0; nt < NT; nt++)
                    acc[mt][nt] = __builtin_amdgcn_mfma_f32_16x16x32_bf16(
                        af[mt], bfr[nt], acc[mt][nt], 0, 0, 0);
        }
        __builtin_amdgcn_s_barrier();
    }

    // epilogue: C/D layout col=lane&15, row=quad*4+reg
#pragma unroll
    for (int mt = 0; mt < MT; mt++) {
        const int rowb = m0 + wr * MT * 16 + mt * 16 + quad * 4;
#pragma unroll
        for (int nt = 0; nt < NT; nt++) {
            const int col = n0 + wc * NT * 16 + nt * 16 + l15;
            const float bv = HASBIAS ? bias[col] : 0.f;
            if (VT && col >= 1024) {
                // V-projection: transposed bf16 write, one short4 (4 s-values)
                short4 sv;
                sv.x = (short)f2b(acc[mt][nt][0] + bv);
                sv.y = (short)f2b(acc[mt][nt][1] + bv);
                sv.z = (short)f2b(acc[mt][nt][2] + bv);
                sv.w = (short)f2b(acc[mt][nt][3] + bv);
                const int bb = rowb >> 11;           // batch (row/2048); uniform per block
                *(short4*)&vtout[(size_t)(bb * 512 + (col - 1024)) * S_ + (rowb & 2047)] = sv;
            } else {
#pragma unroll
                for (int r = 0; r < 4; r++) {
                    const size_t idx = (size_t)(rowb + r) * ldc + col;
                    float v = acc[mt][nt][r] + bv;
                    if (RESADD == 1) v += ((const float*)RES)[idx];
                    if (RESADD == 2) v += b2f(((const unsigned short*)RES)[idx]);
                    if (RELU)   v = fmaxf(v, 0.f);
                    if (OUTB) ((unsigned short*)Cv)[idx] = f2b(v);
                    else      ((float*)Cv)[idx] = v;
                }
            }
        }
    }
}

// ---------------------------------------------------------------------------
// Causal flash attention, K-SPLIT register-P, ZERO-SHUFFLE PV.
// BQ=64, KB=64, grid 1024, 4 waves/block. Wave w = (qh=w>>1, kh=w&1):
// 32 queries x 32 keys, 2 q-tiles sharing every K/V ds_read.
// Softmax->PV handoff with NO transpose: QK^T (S^T trick) leaves lane l with
// P[k=quad*4+r][q=l15]; the A-fragment of v_mfma_f32_16x16x16_bf16 is
// A[m=l15][k=quad*4+j] — the SAME lane mapping (m=q, j=r). PV runs as
// 2x K=16 MFMAs per 32-k chunk with the packed exp2 output used directly.
// Work balance: CU hosts bids {c,c+256,c+512,c+768}; qb(g) makes every
// quadruple sum to 62 tile-iters. Same-bh blocks are stride-32 apart
// (32%8==0) -> already co-located per XCD; no swizzle needed here.
// ---------------------------------------------------------------------------
__global__ __launch_bounds__(256, 4)
void attn_mfma(const unsigned short* __restrict__ qkv,
               const unsigned short* __restrict__ vt,
               unsigned short* __restrict__ ctx)
{
    // Arena (32 KB): [0..8191] Ks dbuf [kr][d] chunk^=(kr&7);
    // [8192..16383] Vs dbuf [dk][kr] chunk^=(dk&7).
    // First 22.5 KB reused as f32 reduction scratch at the end.
    __shared__ unsigned short Arena[16384];

    const int tid  = threadIdx.x;
    const int lane = tid & 63;
    const int w    = tid >> 6;                  // 0..3
    const int quad = lane >> 4;
    const int l15  = lane & 15;
    const int bid  = blockIdx.x;
    const int g    = bid >> 5;
    // CU-balanced qb permutation (bijective over g=0..31)
    const int qb   = (g < 8) ? 31 - g : (g < 16) ? g + 8 : (g < 24) ? 31 - g : g - 24;
    const int bh   = bid & 31;
    const int b    = bh >> 3, hh = bh & 7;
    const int kh   = w & 1;                     // k-chunk (32 keys)
    const int qh   = w >> 1;                    // q-half (32 queries)

    const unsigned short* qbase = qkv + (size_t)(b * S_) * 1536 + hh * 64;
    const unsigned short* kbase = qbase + 512;
    const unsigned short* vtb   = vt + (size_t)bh * 64 * S_;

    bf16x4 ones4;
#pragma unroll
    for (int j = 0; j < 4; j++) ones4[j] = (short)0x3F80;

    auto stage = [&](int kb, int bufi) {
        unsigned short* kd = &Arena[bufi * 4096];
        unsigned short* vd = &Arena[8192 + bufi * 4096];
#pragma unroll
        for (int i = 0; i < 2; i++) {
            const int c = tid + i * 256;
            const int row = c >> 3;
            const int l = (c & 7) ^ (row & 7);
            async_cp16(kbase + (size_t)(kb * 64 + row) * 1536 + l * 8, kd + c * 8);
            async_cp16(vtb + (size_t)row * S_ + kb * 64 + l * 8, vd + c * 8);
        }
    };

    // Q fragments: 2 q-tiles x 2 kc (d chunks)
    bf16x8 qf[2][2];
#pragma unroll
    for (int qt = 0; qt < 2; qt++) {
        const unsigned short* qr = qbase + (size_t)(qb * 64 + qh * 32 + qt * 16 + l15) * 1536;
        qf[qt][0] = *(const bf16x8*)(qr + quad * 8);
        qf[qt][1] = *(const bf16x8*)(qr + 32 + quad * 8);
    }

    f32x4 Oacc[2][5];                           // [qt][0..3]=O dk-tiles, [4]=row-sum
#pragma unroll
    for (int qt = 0; qt < 2; qt++)
#pragma unroll
        for (int i = 0; i < 5; i++) Oacc[qt][i] = (f32x4){0.f, 0.f, 0.f, 0.f};

    stage(0, 0);

    // V b64 fragment address (shorts): per (kt,nt), kr = kh*32+kt*16+quad*4
    const int vch0 = (kh * 4 + (quad >> 1));    // ^(l15&7) applied per read
    const int vsub = (quad & 1) * 4;

    // ---- main loop (kb < qb): no masking
    for (int kb = 0; kb < qb; kb++) {
        stage(kb + 1, (kb + 1) & 1);
        __builtin_amdgcn_s_waitcnt(0x0F74);     // vmcnt(4): current tile done
        __builtin_amdgcn_s_barrier();
        const unsigned short* Kc = &Arena[(kb & 1) * 4096];
        const unsigned short* Vc = &Arena[8192 + (kb & 1) * 4096];

        f32x4 st[2][2];                         // [qt][kt]
#pragma unroll
        for (int qt = 0; qt < 2; qt++)
#pragma unroll
            for (int kt = 0; kt < 2; kt++) st[qt][kt] = (f32x4){0.f, 0.f, 0.f, 0.f};
#pragma unroll
        for (int kc = 0; kc < 2; kc++) {
            const int phys = (kc * 4 + quad) ^ (l15 & 7);
            const bf16x8 kf0 = *(const bf16x8*)&Kc[(kh * 32 + l15) * 64 + phys * 8];
            const bf16x8 kf1 = *(const bf16x8*)&Kc[(kh * 32 + 16 + l15) * 64 + phys * 8];
#pragma unroll
            for (int qt = 0; qt < 2; qt++) {
                st[qt][0] = __builtin_amdgcn_mfma_f32_16x16x32_bf16(kf0, qf[qt][kc], st[qt][0], 0, 0, 0);
                st[qt][1] = __builtin_amdgcn_mfma_f32_16x16x32_bf16(kf1, qf[qt][kc], st[qt][1], 0, 0, 0);
            }
        }

        // V fragments: b64 per (kt,nt)
        bf16x4 vf[2][4];
#pragma unroll
        for (int kt = 0; kt < 2; kt++)
#pragma unroll
            for (int nt = 0; nt < 4; nt++)
                vf[kt][nt] = *(const bf16x4*)&Vc[(nt * 16 + l15) * 64 +
                    (((vch0 + kt * 2) ^ (l15 & 7)) << 3) + vsub];

        // P directly in registers as K=16 A-fragments
#pragma unroll
        for (int qt = 0; qt < 2; qt++) {
#pragma unroll
            for (int kt = 0; kt < 2; kt++) {
                uint2 aw;
                aw.x = packbf(exp2f(st[qt][kt][0]), exp2f(st[qt][kt][1]));
                aw.y = packbf(exp2f(st[qt][kt][2]), exp2f(st[qt][kt][3]));
                const bf16x4 af = __builtin_bit_cast(bf16x4, aw);
#pragma unroll
                for (int nt = 0; nt < 4; nt++)
                    Oacc[qt][nt] = __builtin_amdgcn_mfma_f32_16x16x16bf16_1k(
                        af, vf[kt][nt], Oacc[qt][nt], 0, 0, 0);
                Oacc[qt][4] = __builtin_amdgcn_mfma_f32_16x16x16bf16_1k(
                    af, ones4, Oacc[qt][4], 0, 0, 0);
            }
        }
        __builtin_amdgcn_s_barrier();           // reads done before re-stage
    }

    // ---- peeled diagonal iteration (kb == qb)
    {
        stage(0, (qb + 1) & 1);                 // dummy prefetch (vmcnt uniform)
        __builtin_amdgcn_s_waitcnt(0x0F74);
        __builtin_amdgcn_s_barrier();
        const unsigned short* Kc = &Arena[(qb & 1) * 4096];
        const unsigned short* Vc = &Arena[8192 + (qb & 1) * 4096];

        const bool skipDiag = (kh == 1 && qh == 0);   // k 32..63 > q 0..31: all masked
        const bool fullDiag = (kh == 0 && qh == 1);   // k 0..31 < q 32..63: no mask

        if (!skipDiag) {
            f32x4 st[2][2];
#pragma unroll
            for (int qt = 0; qt < 2; qt++)
#pragma unroll
                for (int kt = 0; kt < 2; kt++) st[qt][kt] = (f32x4){0.f, 0.f, 0.f, 0.f};
#pragma unroll
            for (int kc = 0; kc < 2; kc++) {
                const int phys = (kc * 4 + quad) ^ (l15 & 7);
                const bf16x8 kf0 = *(const bf16x8*)&Kc[(kh * 32 + l15) * 64 + phys * 8];
                const bf16x8 kf1 = *(const bf16x8*)&Kc[(kh * 32 + 16 + l15) * 64 + phys * 8];
#pragma unroll
                for (int qt = 0; qt < 2; qt++) {
                    st[qt][0] = __builtin_amdgcn_mfma_f32_16x16x32_bf16(kf0, qf[qt][kc], st[qt][0], 0, 0, 0);
                    st[qt][1] = __builtin_amdgcn_mfma_f32_16x16x32_bf16(kf1, qf[qt][kc], st[qt][1], 0, 0, 0);
                }
            }

            // per-(qt,kt) tile class: fullDiag -> all full;
            // else (kh==qh): (0,0) tri, (0,1) zero, (1,0) full, (1,1) tri.
            bf16x4 af[2][2];
            if (fullDiag) {
#pragma unroll
                for (int qt = 0; qt < 2; qt++)
#pragma unroll
                    for (int kt = 0; kt < 2; kt++) {
                        uint2 aw;
                        aw.x = packbf(exp2f(st[qt][kt][0]), exp2f(st[qt][kt][1]));
                        aw.y = packbf(exp2f(st[qt][kt][2]), exp2f(st[qt][kt][3]));
                        af[qt][kt] = __builtin_bit_cast(bf16x4, aw);
                    }
            } else {
                float p[4];
                uint2 aw;
#pragma unroll
                for (int r = 0; r < 4; r++)
                    p[r] = (quad * 4 + r > l15) ? 0.f : exp2f(st[0][0][r]);
                aw.x = packbf(p[0], p[1]); aw.y = packbf(p[2], p[3]);
                af[0][0] = __builtin_bit_cast(bf16x4, aw);
                af[0][1] = (bf16x4){0, 0, 0, 0};
                aw.x = packbf(exp2f(st[1][0][0]), exp2f(st[1][0][1]));
                aw.y = packbf(exp2f(st[1][0][2]), exp2f(st[1][0][3]));
                af[1][0] = __builtin_bit_cast(bf16x4, aw);
#pragma unroll
                for (int r = 0; r < 4; r++)
                    p[r] = (quad * 4 + r > l15) ? 0.f : exp2f(st[1][1][r]);
                aw.x = packbf(p[0], p[1]); aw.y = packbf(p[2], p[3]);
                af[1][1] = __builtin_bit_cast(bf16x4, aw);
            }

            bf16x4 vf[2][4];
#pragma unroll
            for (int kt = 0; kt < 2; kt++)
#pragma unroll
                for (int nt = 0; nt < 4; nt++)
                    vf[kt][nt] = *(const bf16x4*)&Vc[(nt * 16 + l15) * 64 +
                        (((vch0 + kt * 2) ^ (l15 & 7)) << 3) + vsub];

#pragma unroll
            for (int qt = 0; qt < 2; qt++)
#pragma unroll
                for (int kt = 0; kt < 2; kt++) {
#pragma unroll
                    for (int nt = 0; nt < 4; nt++)
                        Oacc[qt][nt] = __builtin_amdgcn_mfma_f32_16x16x16bf16_1k(
                            af[qt][kt], vf[kt][nt], Oacc[qt][nt], 0, 0, 0);
                    Oacc[qt][4] = __builtin_amdgcn_mfma_f32_16x16x16bf16_1k(
                        af[qt][kt], ones4, Oacc[qt][4], 0, 0, 0);
                }
        }
    }

    // ---- cross-wave reduction (kh=1 partials -> kh=0), then write ctx
    __syncthreads();
    float* red = (float*)&Arena[0];             // 2 regions x 64 lanes x 44 floats = 22.5 KB
    const int rbase = (qh * 64 + lane) * 44;
    if (kh) {
#pragma unroll
        for (int qt = 0; qt < 2; qt++)
#pragma unroll
            for (int i = 0; i < 5; i++)
                *(f32x4*)&red[rbase + (qt * 5 + i) * 4] = Oacc[qt][i];
    }
    __syncthreads();
    if (!kh) {
#pragma unroll
        for (int qt = 0; qt < 2; qt++)
#pragma unroll
            for (int i = 0; i < 5; i++)
                Oacc[qt][i] += *(const f32x4*)&red[rbase + (qt * 5 + i) * 4];

        unsigned short* cb = ctx + (size_t)(b * S_) * 512 + hh * 64;
#pragma unroll
        for (int qt = 0; qt < 2; qt++) {
            const int orow = qb * 64 + qh * 32 + qt * 16 + quad * 4;
#pragma unroll
            for (int r = 0; r < 4; r++) {
                const float inv = 1.f / Oacc[qt][4][r];
#pragma unroll
                for (int nt = 0; nt < 4; nt++)
                    cb[(size_t)(orow + r) * 512 + nt * 16 + l15] = f2b(Oacc[qt][nt][r] * inv);
            }
        }
    }
}

// ---------------------------------------------------------------------------
// LayerNorm: IB -> bf16 input (else fp32); WF -> fp32 out, WB -> bf16 out.
// 1 wave/row. Input quantization (IB) happens post-residual pre-LN: ~2^-9
// relative perturbation, inside the bf16 error budget.
// ---------------------------------------------------------------------------
template<int IB, int WF, int WB>
__global__ __launch_bounds__(256)
void ln_kernel(const void* __restrict__ sv, const float* __restrict__ g,
               const float* __restrict__ be, float* __restrict__ out,
               unsigned short* __restrict__ outb)
{
    const int wave = threadIdx.x >> 6;
    const int lane = threadIdx.x & 63;
    const int row  = blockIdx.x * 4 + wave;
    const int c0 = lane * 4;

    float v[8];
    if (IB) {
        const unsigned short* ps = (const unsigned short*)sv + (size_t)row * D_;
        const short4 a0 = *(const short4*)(ps + c0);
        const short4 a1 = *(const short4*)(ps + c0 + 256);
        v[0] = b2f((unsigned short)a0.x); v[1] = b2f((unsigned short)a0.y);
        v[2] = b2f((unsigned short)a0.z); v[3] = b2f((unsigned short)a0.w);
        v[4] = b2f((unsigned short)a1.x); v[5] = b2f((unsigned short)a1.y);
        v[6] = b2f((unsigned short)a1.z); v[7] = b2f((unsigned short)a1.w);
    } else {
        const float* ps = (const float*)sv + (size_t)row * D_;
        const float4 a0 = *(const float4*)(ps + c0);
        const float4 a1 = *(const float4*)(ps + c0 + 256);
        v[0] = a0.x; v[1] = a0.y; v[2] = a0.z; v[3] = a0.w;
        v[4] = a1.x; v[5] = a1.y; v[6] = a1.z; v[7] = a1.w;
    }

    float sum = 0.f;
#pragma unroll
    for (int i = 0; i < 8; i++) sum += v[i];
#pragma unroll
    for (int m = 1; m < 64; m <<= 1) sum += __shfl_xor(sum, m);
    const float mu = sum * (1.f / D_);

    float sq = 0.f;
#pragma unroll
    for (int i = 0; i < 8; i++) { const float d = v[i] - mu; sq += d * d; }
#pragma unroll
    for (int m = 1; m < 64; m <<= 1) sq += __shfl_xor(sq, m);
    const float rstd = rsqrtf(sq * (1.f / D_) + EPS_);

    const float4 g0 = *(const float4*)(g + c0);
    const float4 b0 = *(const float4*)(be + c0);
    const float4 g1 = *(const float4*)(g + c0 + 256);
    const float4 b1 = *(const float4*)(be + c0 + 256);

    float o[8];
    o[0] = (v[0] - mu) * rstd * g0.x + b0.x;
    o[1] = (v[1] - mu) * rstd * g0.y + b0.y;
    o[2] = (v[2] - mu) * rstd * g0.z + b0.z;
    o[3] = (v[3] - mu) * rstd * g0.w + b0.w;
    o[4] = (v[4] - mu) * rstd * g1.x + b1.x;
    o[5] = (v[5] - mu) * rstd * g1.y + b1.y;
    o[6] = (v[6] - mu) * rstd * g1.z + b1.z;
    o[7] = (v[7] - mu) * rstd * g1.w + b1.w;

    if (WF) {
        *(float4*)(out + (size_t)row * D_ + c0)       = *(float4*)&o[0];
        *(float4*)(out + (size_t)row * D_ + c0 + 256) = *(float4*)&o[4];
    }
    if (WB) {
        short4 vb0 = (short4){(short)f2b(o[0]), (short)f2b(o[1]), (short)f2b(o[2]), (short)f2b(o[3])};
        short4 vb1 = (short4){(short)f2b(o[4]), (short)f2b(o[5]), (short)f2b(o[6]), (short)f2b(o[7])};
        *(short4*)(outb + (size_t)row * D_ + c0)       = vb0;
        *(short4*)(outb + (size_t)row * D_ + c0 + 256) = vb1;
    }
}

// ---------------------------------------------------------------------------
extern "C" void kernel_launch(void* const* d_in, const int* in_sizes, int n_in,
                              void* d_out, int out_size, void* d_ws, size_t ws_size,
                              hipStream_t stream)
{
    const float* x  = (const float*)d_in[0];
    const float* wq = (const float*)d_in[2];
    const float* bq = (const float*)d_in[3];
    const float* wk = (const float*)d_in[4];
    const float* bk = (const float*)d_in[5];
    const float* wv = (const float*)d_in[6];
    const float* bv = (const float*)d_in[7];
    const float* wo = (const float*)d_in[8];
    const float* bo = (const float*)d_in[9];
    const float* w1 = (const float*)d_in[10];
    const float* b1 = (const float*)d_in[11];
    const float* w2 = (const float*)d_in[12];
    const float* b2 = (const float*)d_in[13];
    const float* g1 = (const float*)d_in[14];
    const float* be1= (const float*)d_in[15];
    const float* g2 = (const float*)d_in[16];
    const float* be2= (const float*)d_in[17];
    float* out = (float*)d_out;

    const size_t MB = 1048576;
    char* w8 = (char*)d_ws;
    unsigned short* wqkvt = (unsigned short*)(w8 + 0);            // 1536x512 bf16
    unsigned short* wot   = (unsigned short*)(w8 + 1572864);      // 512x512
    unsigned short* w1t   = (unsigned short*)(w8 + 2097152);      // 2048x512
    unsigned short* w2t   = (unsigned short*)(w8 + 4194304);      // 512x2048
    float*          bqkv  = (float*)(w8 + 6291456);               // 1536 f32
    unsigned short* qkv   = (unsigned short*)(w8 + 8 * MB);       // 24 MB (later ffn1b)
    unsigned short* ffn1b = qkv;
    unsigned short* xb    = (unsigned short*)(w8 + 40 * MB);      // 8 MB (later ctx)
    unsigned short* ctx   = xb;
    unsigned short* vt    = (unsigned short*)(w8 + 48 * MB);      // 8 MB (later hb)
    unsigned short* hb    = vt;
    unsigned short* preb  = (unsigned short*)(w8 + 56 * MB);      // 8 MB bf16

    const dim3 blk(256);

    // unified preprocessing (1 dispatch)
    prep_kernel<<<dim3(5120), blk, 0, stream>>>(
        x, wq, wk, wv, wo, bq, bk, bv, w1, w2, xb, wqkvt, wot, w1t, w2t, bqkv);

    // qkv = xb @ [wq*SCLQ|wk|wv] + b -> bf16 [M][1536]; V-part written
    // transposed straight into vt (VT=1) — vtrans dispatch eliminated.
    gemm_bf16<2,2,2,4,64,1,0,0,1,1><<<dim3(12, 128), blk, 0, stream>>>(
        xb, wqkvt, bqkv, nullptr, qkv, vt, 512, 512, 512, 1536);

    // causal flash attention (4-wave k-split, zero-shuffle PV) -> ctx bf16
    attn_mfma<<<dim3(1024), blk, 0, stream>>>(qkv, vt, ctx);

    // preb = bf16(x + ctx @ wo + bo)  (fp32 accum+residual, bf16 store)
    gemm_bf16<2,2,2,4,64,1,0,1,1,0><<<dim3(4, 128), blk, 0, stream>>>(
        ctx, wot, bo, x, preb, nullptr, 512, 512, 512, 512);

    // hb = LN(preb) bf16 (residual for FFN carried in bf16 — RNE everywhere)
    ln_kernel<1,0,1><<<dim3(M_ / 4), blk, 0, stream>>>(preb, g1, be1, nullptr, hb);

    // ffn1 = relu(hb @ w1 + b1) -> bf16 [M][2048], BK=64 deep-staged
    gemm_bf16<2,2,2,4,64,1,1,0,1,0><<<dim3(16, 128), blk, 0, stream>>>(
        hb, w1t, b1, nullptr, ffn1b, nullptr, 512, 512, 512, 2048);

    // preb = bf16(hb + ffn1 @ w2 + b2)  (bf16 residual, bf16 store)
    gemm_bf16<2,2,2,4,64,1,0,2,1,0><<<dim3(4, 128), blk, 0, stream>>>(
        ffn1b, w2t, b2, hb, preb, nullptr, 2048, 2048, 2048, 512);

    // out = LN(preb) fp32
    ln_kernel<1,1,0><<<dim3(M_ / 4), blk, 0, stream>>>(preb, g2, be2, out, nullptr);
}